// Round 10
// baseline (1748.804 us; speedup 1.0000x reference)
//
#include <hip/hip_runtime.h>
#include <stdint.h>

// Problem constants (fixed by setup_inputs)
#define KCL 8192      // number of centroids
#define NPT 8192      // number of points
#define FD  4096      // feature dim
#define KF  33554432  // K*F
#define LRC 1e-4f
#define EPSC 1e-8f
#define SLAB 1024     // compact-path slab rows
#define BK  32        // GEMM K-tile

typedef float  f32x4 __attribute__((ext_vector_type(4)));
typedef __fp16 h8    __attribute__((ext_vector_type(8)));
typedef __fp16 h4    __attribute__((ext_vector_type(4)));

struct Scal {
  float Scn;        // sum of cn
  float csum2;      // ||csum||^2 (atomic)
  float cl;         // centroid_loss
  float pl_sum;     // sum of colsum[nearest[n]] (atomic)
  float sum_delta;  // atomic
  int   nonempty;   // atomic
};

__device__ __forceinline__ void gload16(const void* g, void* l) {
  __builtin_amdgcn_global_load_lds((const __attribute__((address_space(1))) void*)g,
                                   (__attribute__((address_space(3))) void*)l, 16, 0, 0);
}

__device__ __forceinline__ float wave_sum(float v) {
  #pragma unroll
  for (int m = 1; m < 64; m <<= 1) v += __shfl_xor(v, m, 64);
  return v;
}
__device__ __forceinline__ double wave_sum(double v) {
  #pragma unroll
  for (int m = 1; m < 64; m <<= 1) v += __shfl_xor(v, m, 64);
  return v;
}

// ---- double-precision row sum-of-squares (compact path only)
__global__ __launch_bounds__(256) void rownorm_k(const float* __restrict__ src,
                                                 double* __restrict__ norms) {
  __shared__ double sred[4];
  const int r = blockIdx.x, t = threadIdx.x;
  const f32x4* row = (const f32x4*)(src + (size_t)r * FD);
  double ss = 0.0;
  #pragma unroll
  for (int q = 0; q < 4; ++q) {
    f32x4 v = row[q * 256 + t];
    ss += (double)(v[0]*v[0] + v[1]*v[1]) + (double)(v[2]*v[2] + v[3]*v[3]);
  }
  ss = wave_sum(ss);
  int wave = t >> 6, lane = t & 63;
  if (lane == 0) sred[wave] = ss;
  __syncthreads();
  if (t == 0) norms[r] = sred[0] + sred[1] + sred[2] + sred[3];
}

// ---- fp32 -> (f16 hi, f16 lo) split (+ optional double row norm / colsum)
template<bool WITH_DOT, bool WNORM>
__global__ __launch_bounds__(256) void prep_rows(
    const float* __restrict__ src, __fp16* __restrict__ hi, __fp16* __restrict__ lo,
    double* __restrict__ norms, const float* __restrict__ csum,
    float* __restrict__ colsum, const Scal* __restrict__ sc)
{
  __shared__ double sred[4], sred2[4];
  const int r = blockIdx.x, t = threadIdx.x;
  const size_t rb = (size_t)r * FD;
  const f32x4* row = (const f32x4*)(src + rb);
  double ss = 0.0, dd = 0.0;
  #pragma unroll
  for (int q = 0; q < 4; ++q) {
    int c4 = q * 256 + t;
    f32x4 v = row[c4];
    h4 hv = __builtin_convertvector(v, h4);
    f32x4 hb = __builtin_convertvector(hv, f32x4);
    h4 lv = __builtin_convertvector(v - hb, h4);
    *(h4*)(hi + rb + (size_t)c4 * 4) = hv;
    *(h4*)(lo + rb + (size_t)c4 * 4) = lv;
    if (WITH_DOT || WNORM)
      ss += (double)(v[0]*v[0] + v[1]*v[1]) + (double)(v[2]*v[2] + v[3]*v[3]);
    if (WITH_DOT) {
      f32x4 cs = *(const f32x4*)(csum + c4 * 4);
      dd += (double)(v[0]*cs[0] + v[1]*cs[1]) + (double)(v[2]*cs[2] + v[3]*cs[3]);
    }
  }
  if (WITH_DOT || WNORM) {
    ss = wave_sum(ss);
    if (WITH_DOT) dd = wave_sum(dd);
    int wave = t >> 6, lane = t & 63;
    if (lane == 0) { sred[wave] = ss; if (WITH_DOT) sred2[wave] = dd; }
    __syncthreads();
    if (t == 0) {
      double S = sred[0] + sred[1] + sred[2] + sred[3];
      if (WNORM) norms[r] = S;
      if (WITH_DOT) {
        double D = sred2[0] + sred2[1] + sred2[2] + sred2[3];
        // colsum[n] = sum_k cn + K*xn - 2*csum.x_n
        colsum[r] = (float)((double)sc->Scn + (double)KCL * S - 2.0 * D);
      }
    }
  }
}

// ---- partial column sums of centroids
__global__ __launch_bounds__(256) void csum_part_k(const float* __restrict__ c,
                                                   float* __restrict__ parts) {
  int f = blockIdx.x * 256 + threadIdx.x;
  int r0 = blockIdx.y * 256;
  float s = 0.f;
  for (int i = 0; i < 256; ++i) s += c[(size_t)(r0 + i) * FD + f];
  parts[(size_t)blockIdx.y * FD + f] = s;
}

__global__ __launch_bounds__(256) void csum_reduce_k(const float* __restrict__ parts,
                                                     float* __restrict__ csum, Scal* sc,
                                                     int nparts) {
  int f = blockIdx.x * 256 + threadIdx.x;
  float s = 0.f;
  for (int j = 0; j < nparts; ++j) s += parts[(size_t)j * FD + f];
  csum[f] = s;
  float sq = wave_sum(s * s);
  __shared__ float sr[4];
  int wave = threadIdx.x >> 6, lane = threadIdx.x & 63;
  if (lane == 0) sr[wave] = sq;
  __syncthreads();
  if (threadIdx.x == 0) atomicAdd(&sc->csum2, sr[0] + sr[1] + sr[2] + sr[3]);
}

__global__ __launch_bounds__(256) void cn_reduce_k(const double* __restrict__ cn, Scal* sc) {
  double s = 0.0;
  for (int i = threadIdx.x; i < KCL; i += 256) s += cn[i];
  s = wave_sum(s);
  __shared__ double sr[4];
  int wave = threadIdx.x >> 6, lane = threadIdx.x & 63;
  if (lane == 0) sr[wave] = s;
  __syncthreads();
  if (threadIdx.x == 0) {
    double S = sr[0] + sr[1] + sr[2] + sr[3];
    sc->Scn = (float)S;
    sc->cl = (float)(1.0 / (2.0 * (double)KCL * S - 2.0 * (double)sc->csum2));
  }
}

// ---- fused f16x2-split MFMA GEMM (16x16x32) + per-(256-kblock, point) argmin
// 256x256 tile, BK=32, 8 waves (2Mx4N), product-split phases, counted vmcnt,
// XOR-swizzled LDS (pre-swizzled global source for global_load_lds).
// TWO barriers per K-tile (round-7 proven schedule), with Al/Bl(t+1) staged in
// ph1 (not ph2) so the wait at barrier (a) has a full extra phase of HBM cover:
//  (a) post-ph0: vmcnt(2)+barrier -> ALL waves' Al,Bl(t) landed (read in ph1/ph2)
//  (b) post-ph2: vmcnt(4)+barrier -> ALL waves' Ah,Bh(t+1) landed; Al,Bl(t+1)
//      stay in flight across the barrier. vmcnt is per-wave; the barrier is what
//      publishes other waves' staging completion (round-6 race lesson).
__global__ __launch_bounds__(512, 2) void gemm_argmin_k(
    const __fp16* __restrict__ Ahi, const __fp16* __restrict__ Alo,
    const __fp16* __restrict__ Bhi, const __fp16* __restrict__ Blo,
    const double* __restrict__ cn,
    double* __restrict__ part_val, int* __restrict__ part_idx,
    int kglob0, int nglob0, int swz)
{
  // 2 dbuf x {Ah,Al,Bh,Bl} x 256x32 f16 = 128 KiB exactly
  __shared__ __fp16 tile[2 * 4 * 8192];

  const int tid  = threadIdx.x;
  const int lane = tid & 63;
  const int w    = tid >> 6;
  const int wr   = w >> 2, wc = w & 3;     // 2 x 4 wave grid
  const int ln15 = lane & 15, lc = lane >> 4;

  int kb, nb;
  if (swz) {
    // supertile raster: 4 supertiles of 16kb x 16nb (128MB working set, L3-fit),
    // gray-code order so consecutive supertiles share a panel; within a supertile
    // each XCD owns 2 nb-columns x 16 kb, kb fastest (B-panel L2-resident).
    int xcd = blockIdx.x & 7, idx = blockIdx.x >> 3;   // idx 0..127
    int st = idx >> 5, i = idx & 31;                    // st 0..3
    kb = (st & 1) * 16 + (i & 15);
    nb = (st >> 1) * 16 + xcd * 2 + (i >> 4);
  } else {    // compact path: plain 2D over slab
    kb = blockIdx.y; nb = blockIdx.x;
  }
  const int k0l = kb * 256, n0l = nb * 256;
  const int k0g = kglob0 + k0l, n0g = nglob0 + n0l;

  const __fp16* gAh = Ahi + (size_t)k0l * FD;
  const __fp16* gAl = Alo + (size_t)k0l * FD;
  const __fp16* gBh = Bhi + (size_t)n0l * FD;
  const __fp16* gBl = Blo + (size_t)n0l * FD;

  // staging: 1024 16B-chunks per array; thread handles chunks tid, tid+512.
  // LDS dest LINEAR (gload_lds requirement); global source pre-swizzled with the
  // same involution the reader applies: pc = cc ^ ((row>>1)&3).
  const int c0 = tid,        r0 = c0 >> 2, sc0 = (c0 & 3) ^ ((r0 >> 1) & 3);
  const int c1 = tid + 512,  r1 = c1 >> 2, sc1 = (c1 & 3) ^ ((r1 >> 1) & 3);
  const size_t gof0 = (size_t)r0 * FD + sc0 * 8;
  const size_t gof1 = (size_t)r1 * FD + sc1 * 8;

  #define TBUF(buf, arr) (tile + (((buf) * 4 + (arr)) << 13))
  #define STAGE(gsrc, buf, arr, fo) do { \
    gload16((gsrc) + gof0 + (fo), TBUF(buf, arr) + c0 * 8); \
    gload16((gsrc) + gof1 + (fo), TBUF(buf, arr) + c1 * 8); } while (0)

  // reader swizzle: uniform per thread (row bits 1..2 mod 4 depend only on ln15)
  const int pcs = (lc ^ ((ln15 >> 1) & 3)) * 8;
  const int abase = wr * 128 + ln15;   // + m*16  (m*16>>1 ≡ 0 mod 4: pc unchanged)
  const int bbase = wc * 64 + ln15;    // + n*16

  f32x4 acc[8][4] = {};
  h8 ah[8], bh[4];

  // prologue: stage tile 0 (order Ah, Bh, Al, Bl), full drain once
  STAGE(gAh, 0, 0, 0); STAGE(gBh, 0, 2, 0); STAGE(gAl, 0, 1, 0); STAGE(gBl, 0, 3, 0);
  asm volatile("s_waitcnt vmcnt(0)" ::: "memory");
  __builtin_amdgcn_s_barrier();

  for (int t = 0; t < FD / BK; ++t) {
    const int cur = t & 1, nxt = cur ^ 1;
    const size_t fo = (size_t)(t + 1) * BK;
    const bool st = (t < FD / BK - 1);

    // ---- phase 0: hi*hi ------------------------------------------------
    {
      const __fp16* sA = TBUF(cur, 0);
      const __fp16* sB = TBUF(cur, 2);
      #pragma unroll
      for (int m = 0; m < 8; ++m) ah[m] = *(const h8*)(sA + (abase + m * 16) * 32 + pcs);
      #pragma unroll
      for (int n = 0; n < 4; ++n) bh[n] = *(const h8*)(sB + (bbase + n * 16) * 32 + pcs);
    }
    if (st) STAGE(gAh, nxt, 0, fo);
    __builtin_amdgcn_s_setprio(1);
    #pragma unroll
    for (int m = 0; m < 8; ++m)
      #pragma unroll
      for (int n = 0; n < 4; ++n)
        acc[m][n] = __builtin_amdgcn_mfma_f32_16x16x32_f16(ah[m], bh[n], acc[m][n], 0, 0, 0);
    __builtin_amdgcn_s_setprio(0);
    // (a) publish Al(t),Bl(t): oldest 4 of my 6 in flight (issued in ph1 of the
    // PREVIOUS tile -> ~1.3 tiles of latency cover). Last tile has only 4
    // outstanding so vmcnt(2) would NOT cover Bl -> drain fully there.
    if (st) asm volatile("s_waitcnt vmcnt(2)" ::: "memory");
    else    asm volatile("s_waitcnt vmcnt(0)" ::: "memory");
    __builtin_amdgcn_sched_barrier(0);
    __builtin_amdgcn_s_barrier();

    // ---- phase 1: hi*lo  (ah regs reused) -------------------------------
    {
      h8 bl[4];
      const __fp16* sB = TBUF(cur, 3);
      #pragma unroll
      for (int n = 0; n < 4; ++n) bl[n] = *(const h8*)(sB + (bbase + n * 16) * 32 + pcs);
      // stage Bh + Al + Bl of t+1 here (Al/Bl moved up from ph2 for extra cover)
      if (st) { STAGE(gBh, nxt, 2, fo); STAGE(gAl, nxt, 1, fo); STAGE(gBl, nxt, 3, fo); }
      __builtin_amdgcn_s_setprio(1);
      #pragma unroll
      for (int m = 0; m < 8; ++m)
        #pragma unroll
        for (int n = 0; n < 4; ++n)
          acc[m][n] = __builtin_amdgcn_mfma_f32_16x16x32_f16(ah[m], bl[n], acc[m][n], 0, 0, 0);
      __builtin_amdgcn_s_setprio(0);
    }

    // ---- phase 2: lo*hi  (bh regs reused) -------------------------------
    {
      h8 al[8];
      const __fp16* sA = TBUF(cur, 1);
      #pragma unroll
      for (int m = 0; m < 8; ++m) al[m] = *(const h8*)(sA + (abase + m * 16) * 32 + pcs);
      __builtin_amdgcn_s_setprio(1);
      #pragma unroll
      for (int m = 0; m < 8; ++m)
        #pragma unroll
        for (int n = 0; n < 4; ++n)
          acc[m][n] = __builtin_amdgcn_mfma_f32_16x16x32_f16(al[m], bh[n], acc[m][n], 0, 0, 0);
      __builtin_amdgcn_s_setprio(0);
      // (b) publish Ah,Bh(t+1); leave Al,Bl(t+1) (4) in flight across the barrier
      asm volatile("s_waitcnt vmcnt(4)" ::: "memory");
      __builtin_amdgcn_sched_barrier(0);
      __builtin_amdgcn_s_barrier();
    }
  }

  // ---- epilogue: reuse dead tile LDS for cn + cross-wave reduction ------
  // D layout (m89-verified): col = lane&15, row = (lane>>4)*4 + j
  double* eCn = (double*)tile;              // 256 doubles
  double* eV  = (double*)(tile + 1024);     // byte off 2048: 512 doubles
  int*    eI  = (int*)(tile + 3072);        // byte off 6144: 512 ints
  __syncthreads();
  if (tid < 256) eCn[tid] = cn[k0g + tid];
  __syncthreads();

  #pragma unroll
  for (int n = 0; n < 4; ++n) {
    double bv = 1e300; int bi = 0x7fffffff;
    #pragma unroll
    for (int m = 0; m < 8; ++m)
      #pragma unroll
      for (int j = 0; j < 4; ++j) {
        int kl = wr * 128 + m * 16 + lc * 4 + j;
        double d = eCn[kl] - 2.0 * (double)acc[m][n][j];
        if (d < bv || (d == bv && kl < bi)) { bv = d; bi = kl; }
      }
    #pragma unroll
    for (int mask = 16; mask < 64; mask <<= 1) {
      double ov = __shfl_xor(bv, mask, 64);
      int    oi = __shfl_xor(bi, mask, 64);
      if (ov < bv || (ov == bv && oi < bi)) { bv = ov; bi = oi; }
    }
    if (lc == 0) {
      int col = wc * 64 + n * 16 + ln15;
      eV[wr * 256 + col] = bv; eI[wr * 256 + col] = bi;
    }
  }
  __syncthreads();
  if (tid < 256) {
    double v0 = eV[tid]; int i0 = eI[tid];
    double v1 = eV[256 + tid]; int i1 = eI[256 + tid];
    if (v1 < v0 || (v1 == v0 && i1 < i0)) { v0 = v1; i0 = i1; }
    part_val[(size_t)(k0g >> 8) * NPT + n0g + tid] = v0;
    part_idx[(size_t)(k0g >> 8) * NPT + n0g + tid] = i0 + k0g;
  }
  #undef TBUF
  #undef STAGE
}

// ---- final argmin over 32 k-blocks; counts; point_loss partial
__global__ __launch_bounds__(256) void nearest_k(
    const double* __restrict__ part_val, const int* __restrict__ part_idx,
    const float* __restrict__ colsum, int* __restrict__ nearest,
    int* __restrict__ counts, Scal* sc)
{
  int n = blockIdx.x * 256 + threadIdx.x;
  double bv = 1e300; int bi = 0x7fffffff;
  for (int kb = 0; kb < 32; ++kb) {
    double v = part_val[(size_t)kb * NPT + n];
    int    i = part_idx[(size_t)kb * NPT + n];
    if (v < bv || (v == bv && i < bi)) { bv = v; bi = i; }
  }
  nearest[n] = bi;
  atomicAdd(&counts[bi], 1);
  // reference semantics: point_loss gathers colsum AT INDEX nearest[n] (K==N)
  float pls = wave_sum(colsum[bi]);
  __shared__ float sr[4];
  int wave = threadIdx.x >> 6, lane = threadIdx.x & 63;
  if (lane == 0) sr[wave] = pls;
  __syncthreads();
  if (threadIdx.x == 0) atomicAdd(&sc->pl_sum, sr[0] + sr[1] + sr[2] + sr[3]);
}

// ---- exclusive scan of counts (single block)
__global__ __launch_bounds__(256) void scan_k(const int* __restrict__ counts,
                                              int* __restrict__ offsets) {
  __shared__ int s[256];
  int t = threadIdx.x;
  int base = t * 32;
  int sum = 0;
  for (int i = 0; i < 32; ++i) sum += counts[base + i];
  s[t] = sum; __syncthreads();
  for (int off = 1; off < 256; off <<= 1) {
    int v = (t >= off) ? s[t - off] : 0;
    __syncthreads();
    s[t] += v;
    __syncthreads();
  }
  int run = s[t] - sum;  // exclusive
  for (int i = 0; i < 32; ++i) { offsets[base + i] = run; run += counts[base + i]; }
}

__global__ __launch_bounds__(256) void fill_k(const int* __restrict__ nearest,
                                              const int* __restrict__ offsets,
                                              int* __restrict__ cursor, int* __restrict__ list) {
  int n = blockIdx.x * 256 + threadIdx.x;
  int k = nearest[n];
  int p = atomicAdd(&cursor[k], 1);
  list[offsets[k] + p] = n;
}

// ---- fused per-cluster mean + delta + Adam + next_centroids row write
__global__ __launch_bounds__(256) void cluster_adam_k(
    const float* __restrict__ x, const float* __restrict__ cen,
    const float* __restrict__ m_in, const float* __restrict__ v_in,
    const float* __restrict__ betas, const int* __restrict__ step,
    const int* __restrict__ counts, const int* __restrict__ offsets,
    const int* __restrict__ list, Scal* sc, float* __restrict__ out)
{
  const int k = blockIdx.x, t = threadIdx.x;
  const int cnt = counts[k];
  const size_t kb = (size_t)k * FD;
  const f32x4* crow = (const f32x4*)(cen + kb);
  f32x4 c4[4];
  #pragma unroll
  for (int q = 0; q < 4; ++q) c4[q] = crow[q * 256 + t];

  float mn, vn, u;
  if (cnt > 0) {
    f32x4 acc[4] = {};
    const int off = offsets[k];
    for (int i = 0; i < cnt; ++i) {
      const f32x4* row = (const f32x4*)(x + (size_t)list[off + i] * FD);
      #pragma unroll
      for (int q = 0; q < 4; ++q) acc[q] += row[q * 256 + t];
    }
    float part = 0.f;
    const float fc = (float)cnt;
    #pragma unroll
    for (int q = 0; q < 4; ++q)
      #pragma unroll
      for (int j = 0; j < 4; ++j) {
        float d = acc[q][j] / fc - c4[q][j];
        part += d * d;
      }
    part = wave_sum(part);
    __shared__ float sr[4];
    __shared__ float sdelta;
    int wave = t >> 6, lane = t & 63;
    if (lane == 0) sr[wave] = part;
    __syncthreads();
    if (t == 0) {
      float dsum = sr[0] + sr[1] + sr[2] + sr[3];
      sdelta = dsum;
      atomicAdd(&sc->sum_delta, dsum);
      atomicAdd(&sc->nonempty, 1);
    }
    __syncthreads();
    float delta_k = sdelta;
    float b0 = betas[0], b1 = betas[1], b2 = betas[2], b3 = betas[3];
    float pl = sc->pl_sum / (float)NPT;
    float g = delta_k + b2 * pl + b3 * sc->cl;
    mn = b0 * m_in[k] + (1.f - b0) * g;
    vn = b1 * v_in[k] + (1.f - b1) * g * g;
    int st = *step;
    float mh = mn / (1.f - powf(b0, (float)st));
    float vh = vn / (1.f - powf(b1, (float)st));
    u = LRC * mh / (sqrtf(vh) + EPSC);
  } else {
    mn = m_in[k]; vn = v_in[k]; u = 0.f;
  }
  if (t == 0) {
    out[3 + (size_t)KF + k] = mn;
    out[3 + (size_t)KF + KCL + k] = vn;
  }
  float* orow = out + 3 + kb;
  #pragma unroll
  for (int q = 0; q < 4; ++q) {
    f32x4 o = c4[q] - u;
    *(f32x4*)(orow + (size_t)(q * 256 + t) * 4) = o;
  }
}

// ---- scalar outputs
__global__ void finalize_k(const Scal* __restrict__ sc, float* __restrict__ out) {
  out[0] = sc->sum_delta / (float)sc->nonempty;
  out[1] = sc->pl_sum / (float)NPT;
  out[2] = sc->cl;
}

extern "C" void kernel_launch(void* const* d_in, const int* in_sizes, int n_in,
                              void* d_out, int out_size, void* d_ws, size_t ws_size,
                              hipStream_t stream) {
  const float* x     = (const float*)d_in[0];
  const float* cen   = (const float*)d_in[1];
  const float* m_in  = (const float*)d_in[2];
  const float* v_in  = (const float*)d_in[3];
  const float* betas = (const float*)d_in[4];
  const int*   step  = (const int*)d_in[5];
  float* out = (float*)d_out;

  char* p = (char*)d_ws;
  auto alloc = [&](size_t b) { char* r = p; p += (b + 255) & ~(size_t)255; return r; };
  Scal* sc      = (Scal*)alloc(sizeof(Scal));
  int* counts   = (int*)alloc(KCL * 4);
  int* cursor   = (int*)alloc(KCL * 4);
  size_t zlen   = (size_t)(p - (char*)d_ws);   // zero block: sc + counts + cursor
  int* offsets  = (int*)alloc(KCL * 4);
  int* list     = (int*)alloc(NPT * 4);
  int* nearest  = (int*)alloc(NPT * 4);
  double* cn    = (double*)alloc(KCL * 8);
  float* colsum = (float*)alloc(NPT * 4);
  float* csum   = (float*)alloc(FD * 4);
  float* cparts = (float*)alloc((size_t)32 * FD * 4);
  double* pval  = (double*)alloc((size_t)32 * NPT * 8);
  int*   pidx   = (int*)alloc((size_t)32 * NPT * 4);
  // split buffers: full (256 MB) if workspace allows, else 1024-row slabs
  const bool fast = ws_size >= (size_t)280 * 1024 * 1024;
  const size_t splitRows = fast ? (size_t)KCL : (size_t)SLAB;
  __fp16* chi = (__fp16*)alloc(splitRows * FD * 2);
  __fp16* clo = (__fp16*)alloc(splitRows * FD * 2);
  __fp16* xhi = (__fp16*)alloc(splitRows * FD * 2);
  __fp16* xlo = (__fp16*)alloc(splitRows * FD * 2);
  (void)in_sizes; (void)n_in; (void)out_size;

  hipMemsetAsync(d_ws, 0, zlen, stream);

  if (fast) {
    // prep(cen) also emits double row norms (folds rownorm pass)
    prep_rows<false, true><<<KCL, 256, 0, stream>>>(cen, chi, clo, cn, nullptr, nullptr, nullptr);
    csum_part_k<<<dim3(16, 32), 256, 0, stream>>>(cen, cparts);
    csum_reduce_k<<<16, 256, 0, stream>>>(cparts, csum, sc, 32);
    cn_reduce_k<<<1, 256, 0, stream>>>(cn, sc);
    prep_rows<true, false><<<NPT, 256, 0, stream>>>(x, xhi, xlo, nullptr, csum, colsum, sc);
    gemm_argmin_k<<<1024, 512, 0, stream>>>(chi, clo, xhi, xlo, cn, pval, pidx, 0, 0, 1);
  } else {
    rownorm_k<<<KCL, 256, 0, stream>>>(cen, cn);
    csum_part_k<<<dim3(16, 32), 256, 0, stream>>>(cen, cparts);
    csum_reduce_k<<<16, 256, 0, stream>>>(cparts, csum, sc, 32);
    cn_reduce_k<<<1, 256, 0, stream>>>(cn, sc);
    for (int q = 0; q < NPT / SLAB; ++q) {
      prep_rows<true, false><<<SLAB, 256, 0, stream>>>(x + (size_t)q * SLAB * FD, xhi, xlo,
                                                       nullptr, csum, colsum + q * SLAB, sc);
      for (int pp = 0; pp < KCL / SLAB; ++pp) {
        prep_rows<false, false><<<SLAB, 256, 0, stream>>>(cen + (size_t)pp * SLAB * FD, chi, clo,
                                                          nullptr, nullptr, nullptr, nullptr);
        gemm_argmin_k<<<dim3(SLAB / 256, SLAB / 256), 512, 0, stream>>>(
            chi, clo, xhi, xlo, cn, pval, pidx, pp * SLAB, q * SLAB, 0);
      }
    }
  }

  nearest_k<<<NPT / 256, 256, 0, stream>>>(pval, pidx, colsum, nearest, counts, sc);
  scan_k<<<1, 256, 0, stream>>>(counts, offsets);
  fill_k<<<NPT / 256, 256, 0, stream>>>(nearest, offsets, cursor, list);
  cluster_adam_k<<<KCL, 256, 0, stream>>>(x, cen, m_in, v_in, betas, step,
                                          counts, offsets, list, sc, out);
  finalize_k<<<1, 1, 0, stream>>>(sc, out);
}

// Round 11
// 1640.237 us; speedup vs baseline: 1.0662x; 1.0662x over previous
//
#include <hip/hip_runtime.h>
#include <stdint.h>

// Problem constants (fixed by setup_inputs)
#define KCL 8192      // number of centroids
#define NPT 8192      // number of points
#define FD  4096      // feature dim
#define KF  33554432  // K*F
#define LRC 1e-4f
#define EPSC 1e-8f
#define SLAB 1024     // compact-path slab rows
#define BK  32        // GEMM K-tile

typedef float  f32x4 __attribute__((ext_vector_type(4)));
typedef __fp16 h8    __attribute__((ext_vector_type(8)));
typedef __fp16 h4    __attribute__((ext_vector_type(4)));

struct Scal {
  float Scn;        // sum of cn
  float csum2;      // ||csum||^2 (atomic)
  float pl_sum;     // sum of colsum[nearest[n]] (atomic)
  float sum_delta;  // atomic
  int   nonempty;   // atomic
};

__device__ __forceinline__ void gload16(const void* g, void* l) {
  __builtin_amdgcn_global_load_lds((const __attribute__((address_space(1))) void*)g,
                                   (__attribute__((address_space(3))) void*)l, 16, 0, 0);
}

__device__ __forceinline__ float wave_sum(float v) {
  #pragma unroll
  for (int m = 1; m < 64; m <<= 1) v += __shfl_xor(v, m, 64);
  return v;
}
__device__ __forceinline__ double wave_sum(double v) {
  #pragma unroll
  for (int m = 1; m < 64; m <<= 1) v += __shfl_xor(v, m, 64);
  return v;
}

// ---- double-precision row sum-of-squares (compact path only)
__global__ __launch_bounds__(256) void rownorm_k(const float* __restrict__ src,
                                                 double* __restrict__ norms) {
  __shared__ double sred[4];
  const int r = blockIdx.x, t = threadIdx.x;
  const f32x4* row = (const f32x4*)(src + (size_t)r * FD);
  double ss = 0.0;
  #pragma unroll
  for (int q = 0; q < 4; ++q) {
    f32x4 v = row[q * 256 + t];
    ss += (double)(v[0]*v[0] + v[1]*v[1]) + (double)(v[2]*v[2] + v[3]*v[3]);
  }
  ss = wave_sum(ss);
  int wave = t >> 6, lane = t & 63;
  if (lane == 0) sred[wave] = ss;
  __syncthreads();
  if (t == 0) norms[r] = sred[0] + sred[1] + sred[2] + sred[3];
}

// ---- fp32 -> (f16 hi, f16 lo) split (+ optional double row norm / colsum)
template<bool WITH_DOT, bool WNORM>
__global__ __launch_bounds__(256) void prep_rows(
    const float* __restrict__ src, __fp16* __restrict__ hi, __fp16* __restrict__ lo,
    double* __restrict__ norms, const float* __restrict__ csum,
    float* __restrict__ colsum, const Scal* __restrict__ sc)
{
  __shared__ double sred[4], sred2[4];
  const int r = blockIdx.x, t = threadIdx.x;
  const size_t rb = (size_t)r * FD;
  const f32x4* row = (const f32x4*)(src + rb);
  double ss = 0.0, dd = 0.0;
  #pragma unroll
  for (int q = 0; q < 4; ++q) {
    int c4 = q * 256 + t;
    f32x4 v = row[c4];
    h4 hv = __builtin_convertvector(v, h4);
    f32x4 hb = __builtin_convertvector(hv, f32x4);
    h4 lv = __builtin_convertvector(v - hb, h4);
    *(h4*)(hi + rb + (size_t)c4 * 4) = hv;
    *(h4*)(lo + rb + (size_t)c4 * 4) = lv;
    if (WITH_DOT || WNORM)
      ss += (double)(v[0]*v[0] + v[1]*v[1]) + (double)(v[2]*v[2] + v[3]*v[3]);
    if (WITH_DOT) {
      f32x4 cs = *(const f32x4*)(csum + c4 * 4);
      dd += (double)(v[0]*cs[0] + v[1]*cs[1]) + (double)(v[2]*cs[2] + v[3]*cs[3]);
    }
  }
  if (WITH_DOT || WNORM) {
    ss = wave_sum(ss);
    if (WITH_DOT) dd = wave_sum(dd);
    int wave = t >> 6, lane = t & 63;
    if (lane == 0) { sred[wave] = ss; if (WITH_DOT) sred2[wave] = dd; }
    __syncthreads();
    if (t == 0) {
      double S = sred[0] + sred[1] + sred[2] + sred[3];
      if (WNORM) norms[r] = S;
      if (WITH_DOT) {
        double D = sred2[0] + sred2[1] + sred2[2] + sred2[3];
        // colsum[n] = sum_k cn + K*xn - 2*csum.x_n
        colsum[r] = (float)((double)sc->Scn + (double)KCL * S - 2.0 * D);
      }
    }
  }
}

// ---- partial column sums of centroids
__global__ __launch_bounds__(256) void csum_part_k(const float* __restrict__ c,
                                                   float* __restrict__ parts) {
  int f = blockIdx.x * 256 + threadIdx.x;
  int r0 = blockIdx.y * 256;
  float s = 0.f;
  for (int i = 0; i < 256; ++i) s += c[(size_t)(r0 + i) * FD + f];
  parts[(size_t)blockIdx.y * FD + f] = s;
}

// ---- csum columns (blocks 0..15) + cn sum -> Scn (block 16)
__global__ __launch_bounds__(256) void csum_reduce_k(const float* __restrict__ parts,
                                                     const double* __restrict__ cn,
                                                     float* __restrict__ csum, Scal* sc,
                                                     int nparts) {
  if (blockIdx.x == 16) {
    double s = 0.0;
    for (int i = threadIdx.x; i < KCL; i += 256) s += cn[i];
    s = wave_sum(s);
    __shared__ double srd[4];
    int wave = threadIdx.x >> 6, lane = threadIdx.x & 63;
    if (lane == 0) srd[wave] = s;
    __syncthreads();
    if (threadIdx.x == 0) sc->Scn = (float)(srd[0] + srd[1] + srd[2] + srd[3]);
    return;
  }
  int f = blockIdx.x * 256 + threadIdx.x;
  float s = 0.f;
  for (int j = 0; j < nparts; ++j) s += parts[(size_t)j * FD + f];
  csum[f] = s;
  float sq = wave_sum(s * s);
  __shared__ float sr[4];
  int wave = threadIdx.x >> 6, lane = threadIdx.x & 63;
  if (lane == 0) sr[wave] = sq;
  __syncthreads();
  if (threadIdx.x == 0) atomicAdd(&sc->csum2, sr[0] + sr[1] + sr[2] + sr[3]);
}

// ---- fused f16x2-split MFMA GEMM (16x16x32) + per-(256-kblock, point) argmin
// 256x256 tile, BK=32, 8 waves (2Mx4N), product-split phases, counted vmcnt,
// XOR-swizzled LDS (pre-swizzled global source for global_load_lds).
// ROUND-7 PROVEN SCHEDULE — two barriers per K-tile, staged 2/2/4:
//  (a) post-ph0: vmcnt(2)+barrier -> ALL waves' Al,Bl(t) landed (read in ph1/ph2)
//  (b) post-ph2: vmcnt(4)+barrier -> ALL waves' Ah,Bh(t+1) landed; Al,Bl(t+1)
//      stay in flight across the barrier. vmcnt is per-wave; the barrier is what
//      publishes other waves' staging completion (round-6 race lesson).
// Round-9 (1-barrier, vmcnt(0) drain) and round-10 (burst staging in ph1) both
// regressed — do not revisit without new counter evidence.
__global__ __launch_bounds__(512, 2) void gemm_argmin_k(
    const __fp16* __restrict__ Ahi, const __fp16* __restrict__ Alo,
    const __fp16* __restrict__ Bhi, const __fp16* __restrict__ Blo,
    const double* __restrict__ cn,
    double* __restrict__ part_val, int* __restrict__ part_idx,
    int kglob0, int nglob0, int swz)
{
  // 2 dbuf x {Ah,Al,Bh,Bl} x 256x32 f16 = 128 KiB exactly
  __shared__ __fp16 tile[2 * 4 * 8192];

  const int tid  = threadIdx.x;
  const int lane = tid & 63;
  const int w    = tid >> 6;
  const int wr   = w >> 2, wc = w & 3;     // 2 x 4 wave grid
  const int ln15 = lane & 15, lc = lane >> 4;

  int kb, nb;
  if (swz) {
    // supertile raster: 4 supertiles of 16kb x 16nb (128MB working set, L3-fit),
    // gray-code order so consecutive supertiles share a panel; within a supertile
    // each XCD owns 2 nb-columns x 16 kb, kb fastest (B-panel L2-resident).
    int xcd = blockIdx.x & 7, idx = blockIdx.x >> 3;   // idx 0..127
    int st = idx >> 5, i = idx & 31;                    // st 0..3
    kb = (st & 1) * 16 + (i & 15);
    nb = (st >> 1) * 16 + xcd * 2 + (i >> 4);
  } else {    // compact path: plain 2D over slab
    kb = blockIdx.y; nb = blockIdx.x;
  }
  const int k0l = kb * 256, n0l = nb * 256;
  const int k0g = kglob0 + k0l, n0g = nglob0 + n0l;

  const __fp16* gAh = Ahi + (size_t)k0l * FD;
  const __fp16* gAl = Alo + (size_t)k0l * FD;
  const __fp16* gBh = Bhi + (size_t)n0l * FD;
  const __fp16* gBl = Blo + (size_t)n0l * FD;

  // staging: 1024 16B-chunks per array; thread handles chunks tid, tid+512.
  // LDS dest LINEAR (gload_lds requirement); global source pre-swizzled with the
  // same involution the reader applies: pc = cc ^ ((row>>1)&3).
  const int c0 = tid,        r0 = c0 >> 2, sc0 = (c0 & 3) ^ ((r0 >> 1) & 3);
  const int c1 = tid + 512,  r1 = c1 >> 2, sc1 = (c1 & 3) ^ ((r1 >> 1) & 3);
  const size_t gof0 = (size_t)r0 * FD + sc0 * 8;
  const size_t gof1 = (size_t)r1 * FD + sc1 * 8;

  #define TBUF(buf, arr) (tile + (((buf) * 4 + (arr)) << 13))
  #define STAGE(gsrc, buf, arr, fo) do { \
    gload16((gsrc) + gof0 + (fo), TBUF(buf, arr) + c0 * 8); \
    gload16((gsrc) + gof1 + (fo), TBUF(buf, arr) + c1 * 8); } while (0)

  // reader swizzle: uniform per thread (row bits 1..2 mod 4 depend only on ln15)
  const int pcs = (lc ^ ((ln15 >> 1) & 3)) * 8;
  const int abase = wr * 128 + ln15;   // + m*16  (m*16>>1 ≡ 0 mod 4: pc unchanged)
  const int bbase = wc * 64 + ln15;    // + n*16

  f32x4 acc[8][4] = {};
  h8 ah[8], bh[4];

  // prologue: stage tile 0 (order Ah, Bh, Al, Bl), full drain once
  STAGE(gAh, 0, 0, 0); STAGE(gBh, 0, 2, 0); STAGE(gAl, 0, 1, 0); STAGE(gBl, 0, 3, 0);
  asm volatile("s_waitcnt vmcnt(0)" ::: "memory");
  __builtin_amdgcn_s_barrier();

  for (int t = 0; t < FD / BK; ++t) {
    const int cur = t & 1, nxt = cur ^ 1;
    const size_t fo = (size_t)(t + 1) * BK;
    const bool st = (t < FD / BK - 1);

    // ---- phase 0: hi*hi ------------------------------------------------
    {
      const __fp16* sA = TBUF(cur, 0);
      const __fp16* sB = TBUF(cur, 2);
      #pragma unroll
      for (int m = 0; m < 8; ++m) ah[m] = *(const h8*)(sA + (abase + m * 16) * 32 + pcs);
      #pragma unroll
      for (int n = 0; n < 4; ++n) bh[n] = *(const h8*)(sB + (bbase + n * 16) * 32 + pcs);
    }
    if (st) STAGE(gAh, nxt, 0, fo);
    __builtin_amdgcn_s_setprio(1);
    #pragma unroll
    for (int m = 0; m < 8; ++m)
      #pragma unroll
      for (int n = 0; n < 4; ++n)
        acc[m][n] = __builtin_amdgcn_mfma_f32_16x16x32_f16(ah[m], bh[n], acc[m][n], 0, 0, 0);
    __builtin_amdgcn_s_setprio(0);
    // (a) publish Al(t),Bl(t): oldest 4 of my 6 in flight; last tile has only
    // 4 outstanding so vmcnt(2) would NOT cover Bl -> drain fully there.
    if (st) asm volatile("s_waitcnt vmcnt(2)" ::: "memory");
    else    asm volatile("s_waitcnt vmcnt(0)" ::: "memory");
    __builtin_amdgcn_sched_barrier(0);
    __builtin_amdgcn_s_barrier();

    // ---- phase 1: hi*lo  (ah regs reused) -------------------------------
    {
      h8 bl[4];
      const __fp16* sB = TBUF(cur, 3);
      #pragma unroll
      for (int n = 0; n < 4; ++n) bl[n] = *(const h8*)(sB + (bbase + n * 16) * 32 + pcs);
      if (st) STAGE(gBh, nxt, 2, fo);
      __builtin_amdgcn_s_setprio(1);
      #pragma unroll
      for (int m = 0; m < 8; ++m)
        #pragma unroll
        for (int n = 0; n < 4; ++n)
          acc[m][n] = __builtin_amdgcn_mfma_f32_16x16x32_f16(ah[m], bl[n], acc[m][n], 0, 0, 0);
      __builtin_amdgcn_s_setprio(0);
    }

    // ---- phase 2: lo*hi  (bh regs reused) -------------------------------
    {
      h8 al[8];
      const __fp16* sA = TBUF(cur, 1);
      #pragma unroll
      for (int m = 0; m < 8; ++m) al[m] = *(const h8*)(sA + (abase + m * 16) * 32 + pcs);
      if (st) { STAGE(gAl, nxt, 1, fo); STAGE(gBl, nxt, 3, fo); }
      __builtin_amdgcn_s_setprio(1);
      #pragma unroll
      for (int m = 0; m < 8; ++m)
        #pragma unroll
        for (int n = 0; n < 4; ++n)
          acc[m][n] = __builtin_amdgcn_mfma_f32_16x16x32_f16(al[m], bh[n], acc[m][n], 0, 0, 0);
      __builtin_amdgcn_s_setprio(0);
      // (b) publish Ah,Bh(t+1); leave Al,Bl(t+1) (4) in flight across the barrier
      asm volatile("s_waitcnt vmcnt(4)" ::: "memory");
      __builtin_amdgcn_sched_barrier(0);
      __builtin_amdgcn_s_barrier();
    }
  }

  // ---- epilogue: reuse dead tile LDS for cn + cross-wave reduction ------
  // D layout (m89-verified): col = lane&15, row = (lane>>4)*4 + j
  double* eCn = (double*)tile;              // 256 doubles
  double* eV  = (double*)(tile + 1024);     // byte off 2048: 512 doubles
  int*    eI  = (int*)(tile + 3072);        // byte off 6144: 512 ints
  __syncthreads();
  if (tid < 256) eCn[tid] = cn[k0g + tid];
  __syncthreads();

  #pragma unroll
  for (int n = 0; n < 4; ++n) {
    double bv = 1e300; int bi = 0x7fffffff;
    #pragma unroll
    for (int m = 0; m < 8; ++m)
      #pragma unroll
      for (int j = 0; j < 4; ++j) {
        int kl = wr * 128 + m * 16 + lc * 4 + j;
        double d = eCn[kl] - 2.0 * (double)acc[m][n][j];
        if (d < bv || (d == bv && kl < bi)) { bv = d; bi = kl; }
      }
    #pragma unroll
    for (int mask = 16; mask < 64; mask <<= 1) {
      double ov = __shfl_xor(bv, mask, 64);
      int    oi = __shfl_xor(bi, mask, 64);
      if (ov < bv || (ov == bv && oi < bi)) { bv = ov; bi = oi; }
    }
    if (lc == 0) {
      int col = wc * 64 + n * 16 + ln15;
      eV[wr * 256 + col] = bv; eI[wr * 256 + col] = bi;
    }
  }
  __syncthreads();
  if (tid < 256) {
    double v0 = eV[tid]; int i0 = eI[tid];
    double v1 = eV[256 + tid]; int i1 = eI[256 + tid];
    if (v1 < v0 || (v1 == v0 && i1 < i0)) { v0 = v1; i0 = i1; }
    part_val[(size_t)(k0g >> 8) * NPT + n0g + tid] = v0;
    part_idx[(size_t)(k0g >> 8) * NPT + n0g + tid] = i0 + k0g;
  }
  #undef TBUF
  #undef STAGE
}

// ---- final argmin over 32 k-blocks; counts; point_loss partial
__global__ __launch_bounds__(256) void nearest_k(
    const double* __restrict__ part_val, const int* __restrict__ part_idx,
    const float* __restrict__ colsum, int* __restrict__ nearest,
    int* __restrict__ counts, Scal* sc)
{
  int n = blockIdx.x * 256 + threadIdx.x;
  double bv = 1e300; int bi = 0x7fffffff;
  for (int kb = 0; kb < 32; ++kb) {
    double v = part_val[(size_t)kb * NPT + n];
    int    i = part_idx[(size_t)kb * NPT + n];
    if (v < bv || (v == bv && i < bi)) { bv = v; bi = i; }
  }
  nearest[n] = bi;
  atomicAdd(&counts[bi], 1);
  // reference semantics: point_loss gathers colsum AT INDEX nearest[n] (K==N)
  float pls = wave_sum(colsum[bi]);
  __shared__ float sr[4];
  int wave = threadIdx.x >> 6, lane = threadIdx.x & 63;
  if (lane == 0) sr[wave] = pls;
  __syncthreads();
  if (threadIdx.x == 0) atomicAdd(&sc->pl_sum, sr[0] + sr[1] + sr[2] + sr[3]);
}

// ---- exclusive scan of counts (single block)
__global__ __launch_bounds__(256) void scan_k(const int* __restrict__ counts,
                                              int* __restrict__ offsets) {
  __shared__ int s[256];
  int t = threadIdx.x;
  int base = t * 32;
  int sum = 0;
  for (int i = 0; i < 32; ++i) sum += counts[base + i];
  s[t] = sum; __syncthreads();
  for (int off = 1; off < 256; off <<= 1) {
    int v = (t >= off) ? s[t - off] : 0;
    __syncthreads();
    s[t] += v;
    __syncthreads();
  }
  int run = s[t] - sum;  // exclusive
  for (int i = 0; i < 32; ++i) { offsets[base + i] = run; run += counts[base + i]; }
}

__global__ __launch_bounds__(256) void fill_k(const int* __restrict__ nearest,
                                              const int* __restrict__ offsets,
                                              int* __restrict__ cursor, int* __restrict__ list) {
  int n = blockIdx.x * 256 + threadIdx.x;
  int k = nearest[n];
  int p = atomicAdd(&cursor[k], 1);
  list[offsets[k] + p] = n;
}

// ---- fused per-cluster mean + delta + Adam + next_centroids row write
__global__ __launch_bounds__(256) void cluster_adam_k(
    const float* __restrict__ x, const float* __restrict__ cen,
    const float* __restrict__ m_in, const float* __restrict__ v_in,
    const float* __restrict__ betas, const int* __restrict__ step,
    const int* __restrict__ counts, const int* __restrict__ offsets,
    const int* __restrict__ list, Scal* sc, float* __restrict__ out)
{
  const int k = blockIdx.x, t = threadIdx.x;
  const int cnt = counts[k];
  const size_t kb = (size_t)k * FD;
  const f32x4* crow = (const f32x4*)(cen + kb);
  f32x4 c4[4];
  #pragma unroll
  for (int q = 0; q < 4; ++q) c4[q] = crow[q * 256 + t];

  float mn, vn, u;
  if (cnt > 0) {
    f32x4 acc[4] = {};
    const int off = offsets[k];
    for (int i = 0; i < cnt; ++i) {
      const f32x4* row = (const f32x4*)(x + (size_t)list[off + i] * FD);
      #pragma unroll
      for (int q = 0; q < 4; ++q) acc[q] += row[q * 256 + t];
    }
    float part = 0.f;
    const float fc = (float)cnt;
    #pragma unroll
    for (int q = 0; q < 4; ++q)
      #pragma unroll
      for (int j = 0; j < 4; ++j) {
        float d = acc[q][j] / fc - c4[q][j];
        part += d * d;
      }
    part = wave_sum(part);
    __shared__ float sr[4];
    __shared__ float sdelta;
    int wave = t >> 6, lane = t & 63;
    if (lane == 0) sr[wave] = part;
    __syncthreads();
    if (t == 0) {
      float dsum = sr[0] + sr[1] + sr[2] + sr[3];
      sdelta = dsum;
      atomicAdd(&sc->sum_delta, dsum);
      atomicAdd(&sc->nonempty, 1);
    }
    __syncthreads();
    float delta_k = sdelta;
    float b0 = betas[0], b1 = betas[1], b2 = betas[2], b3 = betas[3];
    float pl = sc->pl_sum / (float)NPT;
    float cl = (float)(1.0 / (2.0 * (double)KCL * (double)sc->Scn - 2.0 * (double)sc->csum2));
    float g = delta_k + b2 * pl + b3 * cl;
    mn = b0 * m_in[k] + (1.f - b0) * g;
    vn = b1 * v_in[k] + (1.f - b1) * g * g;
    int st = *step;
    float mh = mn / (1.f - powf(b0, (float)st));
    float vh = vn / (1.f - powf(b1, (float)st));
    u = LRC * mh / (sqrtf(vh) + EPSC);
  } else {
    mn = m_in[k]; vn = v_in[k]; u = 0.f;
  }
  if (t == 0) {
    out[3 + (size_t)KF + k] = mn;
    out[3 + (size_t)KF + KCL + k] = vn;
  }
  float* orow = out + 3 + kb;
  #pragma unroll
  for (int q = 0; q < 4; ++q) {
    f32x4 o = c4[q] - u;
    *(f32x4*)(orow + (size_t)(q * 256 + t) * 4) = o;
  }
}

// ---- scalar outputs
__global__ void finalize_k(const Scal* __restrict__ sc, float* __restrict__ out) {
  out[0] = sc->sum_delta / (float)sc->nonempty;
  out[1] = sc->pl_sum / (float)NPT;
  out[2] = (float)(1.0 / (2.0 * (double)KCL * (double)sc->Scn - 2.0 * (double)sc->csum2));
}

extern "C" void kernel_launch(void* const* d_in, const int* in_sizes, int n_in,
                              void* d_out, int out_size, void* d_ws, size_t ws_size,
                              hipStream_t stream) {
  const float* x     = (const float*)d_in[0];
  const float* cen   = (const float*)d_in[1];
  const float* m_in  = (const float*)d_in[2];
  const float* v_in  = (const float*)d_in[3];
  const float* betas = (const float*)d_in[4];
  const int*   step  = (const int*)d_in[5];
  float* out = (float*)d_out;

  char* p = (char*)d_ws;
  auto alloc = [&](size_t b) { char* r = p; p += (b + 255) & ~(size_t)255; return r; };
  Scal* sc      = (Scal*)alloc(sizeof(Scal));
  int* counts   = (int*)alloc(KCL * 4);
  int* cursor   = (int*)alloc(KCL * 4);
  size_t zlen   = (size_t)(p - (char*)d_ws);   // zero block: sc + counts + cursor
  int* offsets  = (int*)alloc(KCL * 4);
  int* list     = (int*)alloc(NPT * 4);
  int* nearest  = (int*)alloc(NPT * 4);
  double* cn    = (double*)alloc(KCL * 8);
  float* colsum = (float*)alloc(NPT * 4);
  float* csum   = (float*)alloc(FD * 4);
  float* cparts = (float*)alloc((size_t)32 * FD * 4);
  double* pval  = (double*)alloc((size_t)32 * NPT * 8);
  int*   pidx   = (int*)alloc((size_t)32 * NPT * 4);
  // split buffers: full (256 MB) if workspace allows, else 1024-row slabs
  const bool fast = ws_size >= (size_t)280 * 1024 * 1024;
  const size_t splitRows = fast ? (size_t)KCL : (size_t)SLAB;
  __fp16* chi = (__fp16*)alloc(splitRows * FD * 2);
  __fp16* clo = (__fp16*)alloc(splitRows * FD * 2);
  __fp16* xhi = (__fp16*)alloc(splitRows * FD * 2);
  __fp16* xlo = (__fp16*)alloc(splitRows * FD * 2);
  (void)in_sizes; (void)n_in; (void)out_size;

  hipMemsetAsync(d_ws, 0, zlen, stream);

  if (fast) {
    // prep(cen) also emits double row norms (folds rownorm pass)
    prep_rows<false, true><<<KCL, 256, 0, stream>>>(cen, chi, clo, cn, nullptr, nullptr, nullptr);
    csum_part_k<<<dim3(16, 32), 256, 0, stream>>>(cen, cparts);
    csum_reduce_k<<<17, 256, 0, stream>>>(cparts, cn, csum, sc, 32);
    prep_rows<true, false><<<NPT, 256, 0, stream>>>(x, xhi, xlo, nullptr, csum, colsum, sc);
    gemm_argmin_k<<<1024, 512, 0, stream>>>(chi, clo, xhi, xlo, cn, pval, pidx, 0, 0, 1);
  } else {
    rownorm_k<<<KCL, 256, 0, stream>>>(cen, cn);
    csum_part_k<<<dim3(16, 32), 256, 0, stream>>>(cen, cparts);
    csum_reduce_k<<<17, 256, 0, stream>>>(cparts, cn, csum, sc, 32);
    for (int q = 0; q < NPT / SLAB; ++q) {
      prep_rows<true, false><<<SLAB, 256, 0, stream>>>(x + (size_t)q * SLAB * FD, xhi, xlo,
                                                       nullptr, csum, colsum + q * SLAB, sc);
      for (int pp = 0; pp < KCL / SLAB; ++pp) {
        prep_rows<false, false><<<SLAB, 256, 0, stream>>>(cen + (size_t)pp * SLAB * FD, chi, clo,
                                                          nullptr, nullptr, nullptr, nullptr);
        gemm_argmin_k<<<dim3(SLAB / 256, SLAB / 256), 512, 0, stream>>>(
            chi, clo, xhi, xlo, cn, pval, pidx, pp * SLAB, q * SLAB, 0);
      }
    }
  }

  nearest_k<<<NPT / 256, 256, 0, stream>>>(pval, pidx, colsum, nearest, counts, sc);
  scan_k<<<1, 256, 0, stream>>>(counts, offsets);
  fill_k<<<NPT / 256, 256, 0, stream>>>(nearest, offsets, cursor, list);
  cluster_adam_k<<<KCL, 256, 0, stream>>>(x, cen, m_in, v_in, betas, step,
                                          counts, offsets, list, sc, out);
  finalize_k<<<1, 1, 0, stream>>>(sc, out);
}